// Round 4
// baseline (690.420 us; speedup 1.0000x reference)
//
#include <hip/hip_runtime.h>
#include <hip/hip_bf16.h>
#include <math.h>

// Problem constants: B=2, N=16384, K=24, d_points=64, d_model=128, POS_DIM=60
constexpr int BB = 2;
constexpr int NN = 16384;
constexpr int KK = 24;
constexpr int DM = 128;
constexpr int DP = 64;

constexpr int PPB = 4;           // points per fused block
constexpr int RR  = PPB * KK;    // 96 matmul rows per block (6 x 16, no pad rows)

typedef __bf16 v8bf __attribute__((ext_vector_type(8)));
typedef float  v4f  __attribute__((ext_vector_type(4)));

// A-operand LDS leading dims: +8 bf16 pad keeps 16B alignment and shifts
// consecutive rows by 4 banks -> quad-lane ds_read_b128 is only 2-way (free).
constexpr int LDA128 = 136;
constexpr int LDA64  = 72;

// bf16 weight buffer layout in ws (element offsets from wbuf):
//   fc1t 128x64 @0, d1t 128x64 @8192, d2t 128x128 @16384,
//   g1t @32768, g2t @49152, fc2t (transposed [f][g]) @65536; total 81920 bf16.
constexpr int OFF_FC1T = 0;
constexpr int OFF_D1T  = 8192;
constexpr int OFF_D2T  = 16384;
constexpr int OFF_G1T  = 32768;
constexpr int OFF_G2T  = 49152;
constexpr int OFF_FC2T = 65536;
constexpr int W_TOTAL  = 81920;

// ---------------------------------------------------------------------------
// Weight prep: transpose + cast to bf16. wbuf = d_ws + B*N*DM bf16 elems.
// ---------------------------------------------------------------------------
__global__ __launch_bounds__(256) void prep_kernel(
    const float* __restrict__ fc1_w, const float* __restrict__ fc2_w,
    const float* __restrict__ d1_w,  const float* __restrict__ d2_w,
    const float* __restrict__ g1_w,  const float* __restrict__ g2_w,
    __hip_bfloat16* __restrict__ wbuf)
{
    const int i = blockIdx.x * 256 + threadIdx.x;
    if (i >= W_TOTAL) return;
    float v;
    if (i < OFF_D1T) {                       // fc1t[n][k] = fc1_w[k][n], 64x128 src
        const int j = i, n = j >> 6, k = j & 63;
        v = fc1_w[k * DM + n];
    } else if (i < OFF_D2T) {                // d1t[n][k] = d1_w[k][n], 60x128 src, pad k>=60
        const int j = i - OFF_D1T, n = j >> 6, k = j & 63;
        v = (k < 60) ? d1_w[k * DM + n] : 0.f;
    } else if (i < OFF_G1T) {
        const int j = i - OFF_D2T, n = j >> 7, k = j & 127;
        v = d2_w[k * DM + n];
    } else if (i < OFF_G2T) {
        const int j = i - OFF_G1T, n = j >> 7, k = j & 127;
        v = g1_w[k * DM + n];
    } else if (i < OFF_FC2T) {
        const int j = i - OFF_G2T, n = j >> 7, k = j & 127;
        v = g2_w[k * DM + n];
    } else {                                 // fc2t[f][g] = fc2_w[g][f]
        const int j = i - OFF_FC2T, f = j >> 7, g = j & 127;
        v = fc2_w[g * DM + f];
    }
    wbuf[i] = __float2bfloat16(v);
}

// ---------------------------------------------------------------------------
// (MT*16)x32 output tile per wave. PAIRED-COLUMN fragment assignment:
// b0 carries logical col c0+2*ln, b1 carries c0+2*ln+1 (adjacent pair).
// Union over lanes is still cols [c0,c0+32); epilogues get adjacent-column
// pairs per lane -> packed b32 LDS writes / dwordx2 global stores.
// MFMA layouts (verified m89/m120):
//   A: m=lane&15, k=quad*8+j ; B: k=quad*8+j ; D: row=quad*4+r.
// ---------------------------------------------------------------------------
template <int MT, int NKT, int LDA, int LDB>
__device__ __forceinline__ void mm_frags(
    const __hip_bfloat16* As, const __hip_bfloat16* __restrict__ Bt,
    int c0, int lane, v4f (&acc)[MT][2])
{
    const int ln = lane & 15, quad = lane >> 4;
    #pragma unroll
    for (int mt = 0; mt < MT; ++mt) {
        acc[mt][0] = (v4f)0.f;
        acc[mt][1] = (v4f)0.f;
    }
    __builtin_amdgcn_s_setprio(1);
    #pragma unroll
    for (int kt = 0; kt < NKT; ++kt) {
        const int k0 = kt * 32 + quad * 8;
        const v8bf b0 = *(const v8bf*)(Bt + (c0 + 2 * ln) * LDB + k0);
        const v8bf b1 = *(const v8bf*)(Bt + (c0 + 2 * ln + 1) * LDB + k0);
        #pragma unroll
        for (int mt = 0; mt < MT; ++mt) {
            const v8bf a = *(const v8bf*)(As + (mt * 16 + ln) * LDA + k0);
            acc[mt][0] = __builtin_amdgcn_mfma_f32_16x16x32_bf16(a, b0, acc[mt][0], 0, 0, 0);
            acc[mt][1] = __builtin_amdgcn_mfma_f32_16x16x32_bf16(a, b1, acc[mt][1], 0, 0, 0);
        }
    }
    __builtin_amdgcn_s_setprio(0);
}

// pack 2 f32 -> 1 u32 of 2 bf16 (RNE); un{lo,hi}: bf16 halves -> f32 (exact)
__device__ __forceinline__ unsigned pk2(float a, float b) {
    __hip_bfloat16 ha = __float2bfloat16(a), hb = __float2bfloat16(b);
    unsigned ua = *reinterpret_cast<unsigned short*>(&ha);
    unsigned ub = *reinterpret_cast<unsigned short*>(&hb);
    return ua | (ub << 16);
}
__device__ __forceinline__ float unlo(unsigned u) {
    unsigned v = u << 16; return *reinterpret_cast<float*>(&v);
}
__device__ __forceinline__ float unhi(unsigned u) {
    unsigned v = u & 0xffff0000u; return *reinterpret_cast<float*>(&v);
}

// ---------------------------------------------------------------------------
// Kernel 1: x_bf = bf16(features @ fc1_w + fc1_b), 32 rows per block, MFMA.
// Paired-col epilogue: one packed dword store per (mt,r).
// ---------------------------------------------------------------------------
__global__ __launch_bounds__(256) void fc1_kernel(
    const float* __restrict__ feat,
    const __hip_bfloat16* __restrict__ fc1t,
    const float* __restrict__ fc1_b,
    __hip_bfloat16* __restrict__ x_bf)
{
    __shared__ alignas(16) __hip_bfloat16 s_f[32 * LDA64];
    const int tid = threadIdx.x;
    const int r0  = blockIdx.x * 32;
    for (int e = tid; e < 32 * DP; e += 256) {
        const int r = e >> 6, k = e & 63;
        s_f[r * LDA64 + k] = __float2bfloat16(feat[(size_t)(r0 + r) * DP + k]);
    }
    __syncthreads();
    const int w = tid >> 6, lane = tid & 63;
    const int ln = lane & 15, quad = lane >> 4;
    const int c0 = w * 32;
    v4f acc[2][2];
    mm_frags<2, 2, LDA64, 64>(s_f, fc1t, c0, lane, acc);
    {
        const int col0 = c0 + 2 * ln;
        const float2 bb = *(const float2*)(fc1_b + col0);
        #pragma unroll
        for (int mt = 0; mt < 2; ++mt)
            #pragma unroll
            for (int r = 0; r < 4; ++r) {
                const int row = mt * 16 + quad * 4 + r;
                *reinterpret_cast<unsigned*>(x_bf + (size_t)(r0 + row) * DM + col0) =
                    pk2(acc[mt][0][r] + bb.x, acc[mt][1][r] + bb.y);
            }
    }
}

// ---------------------------------------------------------------------------
// Kernel 2: fused pipeline, PPB=4 points (96 rows), 256 thr, 4 blocks/CU.
// LDS (27,136 B): s_A (in-place matmul buffer, idx in tail) + s_xm only.
// kv lives ENTIRELY in registers: one dword gather per (mt,r) delivers the
// thread's adjacent col pair in fragment layout (s_Z deleted). Softmax in
// registers (shfl_xor 16/32); kv+pe carried as 24 packed-bf16 dwords.
// Phases: 0 idx/xm/sincos | 1 kv-gather-issue + mm1(t) | 2 mm2(pe->h, kv+=pe)
//   | 3 mm3(u) | 4+5 mm4 + reg-softmax + attn + wsum -> res16 | 6 fc2 MFMA
// ---------------------------------------------------------------------------
__global__ __launch_bounds__(256, 4) void fused_kernel(
    const __hip_bfloat16* __restrict__ x_bf,
    const float* __restrict__ xyz,
    const int*   __restrict__ knn_idx,
    const float* __restrict__ knn_xyz,
    const __hip_bfloat16* __restrict__ wbuf,
    const float* __restrict__ d1_b, const float* __restrict__ d2_b,
    const float* __restrict__ g1_b, const float* __restrict__ g2_b,
    const float* __restrict__ fc2_b,
    float* __restrict__ out_res,
    float* __restrict__ out_attn)
{
    __shared__ alignas(16) __hip_bfloat16 s_A[RR * LDA128];
    __shared__ alignas(16) __hip_bfloat16 s_xm[PPB * DM];

    __hip_bfloat16* s_ge = s_A;                               // stride LDA64, dead after mm1
    int* s_idx = reinterpret_cast<int*>(s_A + RR * LDA64);    // tail (16B-aligned), read in ph1

    const int tid = threadIdx.x;
    const int pt0 = blockIdx.x * PPB;
    const int b   = pt0 >> 14;
    const int w = tid >> 6, lane = tid & 63;
    const int ln = lane & 15, quad = lane >> 4;
    const int c0 = w * 32;
    const int col0 = c0 + 2 * ln;         // this lane's adjacent logical col pair
    const bool lo = (quad < 2);           // straddler-mt routing: quads 0-1 = low point

    // ---- phase 0: idx, xm, sincos embedding ----
    if (tid < RR) s_idx[tid] = knn_idx[(size_t)pt0 * KK + tid];
    if (tid < PPB * DM / 8)
        *reinterpret_cast<v8bf*>(s_xm + tid * 8) =
            *(const v8bf*)(x_bf + (size_t)pt0 * DM + tid * 8);
    if (tid < RR)                         // zero k-pad cols 60..63 of g_emb
        *reinterpret_cast<uint2*>(s_ge + tid * LDA64 + 60) = make_uint2(0u, 0u);
    for (int e = tid; e < RR * 30; e += 256) {
        const int row = e / 30;
        const int rem = e - row * 30;
        const int c = rem / 10;
        const int i = rem - c * 10;
        const int g = pt0 + row / 24;
        const float pv = xyz[(size_t)g * 3 + c] - knn_xyz[((size_t)pt0 * KK + row) * 3 + c];
        const float om = exp2f(-(float)i * 1.3287712379549449f); // 10000^(-i/10)
        float sv, cv;
        __sincosf(pv * om, &sv, &cv);
        s_ge[row * LDA64 + c * 20 + i]      = __float2bfloat16(sv);
        s_ge[row * LDA64 + c * 20 + 10 + i] = __float2bfloat16(cv);
    }
    __syncthreads();

    v4f acc[6][2];

    // ---- phase 1: kv gather direct to regs (issue early) || mm1 ----
    unsigned kvg[6][4];                   // packed bf16 pair (col0,col0+1) per row
    {
        const __hip_bfloat16* xb = x_bf + (size_t)b * NN * DM + col0;
        #pragma unroll
        for (int mt = 0; mt < 6; ++mt) {
            const int4 iv = *reinterpret_cast<const int4*>(&s_idx[mt * 16 + quad * 4]);
            kvg[mt][0] = *(const unsigned*)(xb + (size_t)iv.x * DM);
            kvg[mt][1] = *(const unsigned*)(xb + (size_t)iv.y * DM);
            kvg[mt][2] = *(const unsigned*)(xb + (size_t)iv.z * DM);
            kvg[mt][3] = *(const unsigned*)(xb + (size_t)iv.w * DM);
        }
    }
    mm_frags<6, 2, LDA64, 64>(s_A, wbuf + OFF_D1T, c0, lane, acc);
    __syncthreads();                      // ge/idx reads done -> safe to overwrite s_A
    {
        const float2 bb = *(const float2*)(d1_b + col0);
        #pragma unroll
        for (int mt = 0; mt < 6; ++mt) {
            const int row0 = mt * 16 + quad * 4;
            #pragma unroll
            for (int r = 0; r < 4; ++r)
                *reinterpret_cast<unsigned*>(&s_A[(row0 + r) * LDA128 + col0]) =
                    pk2(fmaxf(acc[mt][0][r] + bb.x, 0.f), fmaxf(acc[mt][1][r] + bb.y, 0.f));
        }
    }
    __syncthreads();

    // ---- phase 2: pe = t@d2+b; h = xm-kv+pe -> A; kvg <- packed kv+pe ----
    mm_frags<6, 4, LDA128, DM>(s_A, wbuf + OFF_D2T, c0, lane, acc);
    __syncthreads();                      // t reads done
    {
        const float2 bb = *(const float2*)(d2_b + col0);
        constexpr int pl_[6] = {0,0,1,2,2,3};
        constexpr int ph_[6] = {0,1,1,2,3,3};
        #pragma unroll
        for (int mt = 0; mt < 6; ++mt) {
            const int row0 = mt * 16 + quad * 4;
            const int p = (pl_[mt] == ph_[mt]) ? pl_[mt] : (lo ? pl_[mt] : ph_[mt]);
            const unsigned xw = *reinterpret_cast<const unsigned*>(&s_xm[p * DM + col0]);
            const float xm0 = unlo(xw), xm1 = unhi(xw);
            #pragma unroll
            for (int r = 0; r < 4; ++r) {
                const float pe0 = acc[mt][0][r] + bb.x;
                const float pe1 = acc[mt][1][r] + bb.y;
                const float kv0 = unlo(kvg[mt][r]);
                const float kv1 = unhi(kvg[mt][r]);
                *reinterpret_cast<unsigned*>(&s_A[(row0 + r) * LDA128 + col0]) =
                    pk2(xm0 - kv0 + pe0, xm1 - kv1 + pe1);
                kvg[mt][r] = pk2(kv0 + pe0, kv1 + pe1);
            }
        }
    }
    __syncthreads();

    // ---- phase 3: u = relu(h@g1+b) -> A ----
    mm_frags<6, 4, LDA128, DM>(s_A, wbuf + OFF_G1T, c0, lane, acc);
    __syncthreads();
    {
        const float2 bb = *(const float2*)(g1_b + col0);
        #pragma unroll
        for (int mt = 0; mt < 6; ++mt) {
            const int row0 = mt * 16 + quad * 4;
            #pragma unroll
            for (int r = 0; r < 4; ++r)
                *reinterpret_cast<unsigned*>(&s_A[(row0 + r) * LDA128 + col0]) =
                    pk2(fmaxf(acc[mt][0][r] + bb.x, 0.f), fmaxf(acc[mt][1][r] + bb.y, 0.f));
        }
    }
    __syncthreads();

    // ---- phase 4+5: logits in regs -> register softmax -> attn + wsum ----
    mm_frags<6, 4, LDA128, DM>(s_A, wbuf + OFF_G2T, c0, lane, acc);
    float rp[4][2];
    {
        // log2-domain: softmax_e(x*iscl) == softmax via exp2(x*C), C=iscl*log2e
        const float C = 0.08838834764831845f * 1.4426950408889634f;
        const float2 gb = *(const float2*)(g2_b + col0);
        const float sb0 = gb.x * C, sb1 = gb.y * C;
        #pragma unroll
        for (int mt = 0; mt < 6; ++mt)
            #pragma unroll
            for (int r = 0; r < 4; ++r) {
                acc[mt][0][r] = fmaf(acc[mt][0][r], C, sb0);
                acc[mt][1][r] = fmaf(acc[mt][1][r], C, sb1);
            }

        constexpr int pl_[6] = {0,0,1,2,2,3};
        constexpr int ph_[6] = {0,1,1,2,3,3};

        // per-point max (static routing) then quad reduce
        float mx[4][2];
        #pragma unroll
        for (int p = 0; p < 4; ++p) { mx[p][0] = -1e30f; mx[p][1] = -1e30f; }
        #pragma unroll
        for (int mt = 0; mt < 6; ++mt)
            #pragma unroll
            for (int nl = 0; nl < 2; ++nl) {
                const float m4 = fmaxf(fmaxf(acc[mt][nl][0], acc[mt][nl][1]),
                                       fmaxf(acc[mt][nl][2], acc[mt][nl][3]));
                if (pl_[mt] == ph_[mt]) {
                    mx[pl_[mt]][nl] = fmaxf(mx[pl_[mt]][nl], m4);
                } else {
                    mx[pl_[mt]][nl] = fmaxf(mx[pl_[mt]][nl], lo ? m4 : -1e30f);
                    mx[ph_[mt]][nl] = fmaxf(mx[ph_[mt]][nl], lo ? -1e30f : m4);
                }
            }
        #pragma unroll
        for (int p = 0; p < 4; ++p)
            #pragma unroll
            for (int nl = 0; nl < 2; ++nl) {
                float v = mx[p][nl];
                v = fmaxf(v, __shfl_xor(v, 16));
                v = fmaxf(v, __shfl_xor(v, 32));
                mx[p][nl] = v;
            }

        // e = exp2(L - mx), per-point sums
        float sm[4][2];
        #pragma unroll
        for (int p = 0; p < 4; ++p) { sm[p][0] = 0.f; sm[p][1] = 0.f; }
        #pragma unroll
        for (int mt = 0; mt < 6; ++mt)
            #pragma unroll
            for (int nl = 0; nl < 2; ++nl) {
                const float mxv = (pl_[mt] == ph_[mt]) ? mx[pl_[mt]][nl]
                                  : (lo ? mx[pl_[mt]][nl] : mx[ph_[mt]][nl]);
                float es = 0.f;
                #pragma unroll
                for (int r = 0; r < 4; ++r) {
                    const float e = exp2f(acc[mt][nl][r] - mxv);
                    acc[mt][nl][r] = e;
                    es += e;
                }
                if (pl_[mt] == ph_[mt]) {
                    sm[pl_[mt]][nl] += es;
                } else {
                    sm[pl_[mt]][nl] += lo ? es : 0.f;
                    sm[ph_[mt]][nl] += lo ? 0.f : es;
                }
            }
        #pragma unroll
        for (int p = 0; p < 4; ++p)
            #pragma unroll
            for (int nl = 0; nl < 2; ++nl) {
                float v = sm[p][nl];
                v += __shfl_xor(v, 16);
                v += __shfl_xor(v, 32);
                sm[p][nl] = 1.f / v;       // inv-sum
            }

        // attn = e*inv -> global dwordx2 (adjacent col pair); wsum from kvg
        #pragma unroll
        for (int p = 0; p < 4; ++p) { rp[p][0] = 0.f; rp[p][1] = 0.f; }
        float* abase = out_attn + (size_t)pt0 * KK * DM + col0;  // p cancels in row idx
        #pragma unroll
        for (int mt = 0; mt < 6; ++mt) {
            const int rowg0 = mt * 16 + quad * 4;
            const float inv0 = (pl_[mt] == ph_[mt]) ? sm[pl_[mt]][0]
                               : (lo ? sm[pl_[mt]][0] : sm[ph_[mt]][0]);
            const float inv1 = (pl_[mt] == ph_[mt]) ? sm[pl_[mt]][1]
                               : (lo ? sm[pl_[mt]][1] : sm[ph_[mt]][1]);
            float ws0 = 0.f, ws1 = 0.f;
            #pragma unroll
            for (int r = 0; r < 4; ++r) {
                const float a0 = acc[mt][0][r] * inv0;
                const float a1 = acc[mt][1][r] * inv1;
                float2 st; st.x = a0; st.y = a1;
                *reinterpret_cast<float2*>(abase + (size_t)(rowg0 + r) * DM) = st;
                ws0 = fmaf(a0, unlo(kvg[mt][r]), ws0);
                ws1 = fmaf(a1, unhi(kvg[mt][r]), ws1);
            }
            if (pl_[mt] == ph_[mt]) {
                rp[pl_[mt]][0] += ws0; rp[pl_[mt]][1] += ws1;
            } else {
                rp[pl_[mt]][0] += lo ? ws0 : 0.f;  rp[pl_[mt]][1] += lo ? ws1 : 0.f;
                rp[ph_[mt]][0] += lo ? 0.f : ws0;  rp[ph_[mt]][1] += lo ? 0.f : ws1;
            }
        }
        #pragma unroll
        for (int p = 0; p < 4; ++p)
            #pragma unroll
            for (int nl = 0; nl < 2; ++nl) {
                float v = rp[p][nl];
                v += __shfl_xor(v, 16);
                v += __shfl_xor(v, 32);
                rp[p][nl] = v;
            }
    }
    __syncthreads();                      // all mm4 A-reads done -> reuse rows 0..3
    if (quad == 0) {                      // res16: rows 0..3 real; 4..15 stale u (finite)
        #pragma unroll
        for (int p = 0; p < 4; ++p)
            *reinterpret_cast<unsigned*>(&s_A[p * LDA128 + col0]) =
                pk2(rp[p][0], rp[p][1]);
    }
    __syncthreads();

    // ---- phase 6: out_res rows = res16 @ fc2t via one 16-row MFMA tile ----
    {
        v4f a2[1][2];
        mm_frags<1, 4, LDA128, DM>(s_A, wbuf + OFF_FC2T, c0, lane, a2);
        if (quad == 0) {                  // D rows 0..3 are the real points
            const float2 bb = *(const float2*)(fc2_b + col0);
            #pragma unroll
            for (int r = 0; r < 4; ++r) {
                const unsigned xw = *reinterpret_cast<const unsigned*>(&s_xm[r * DM + col0]);
                float2 o;
                o.x = a2[0][0][r] + bb.x + unlo(xw);
                o.y = a2[0][1][r] + bb.y + unhi(xw);
                *reinterpret_cast<float2*>(out_res + (size_t)(pt0 + r) * DM + col0) = o;
            }
        }
    }
}

// ---------------------------------------------------------------------------
extern "C" void kernel_launch(void* const* d_in, const int* in_sizes, int n_in,
                              void* d_out, int out_size, void* d_ws, size_t ws_size,
                              hipStream_t stream)
{
    const float* features = (const float*)d_in[0];
    const float* xyz      = (const float*)d_in[1];
    const int*   knn_idx  = (const int*)  d_in[2];
    const float* knn_xyz  = (const float*)d_in[3];
    const float* fc1_w    = (const float*)d_in[4];
    const float* fc1_b    = (const float*)d_in[5];
    const float* fc2_w    = (const float*)d_in[6];
    const float* fc2_b    = (const float*)d_in[7];
    const float* d1_w     = (const float*)d_in[8];
    const float* d1_b     = (const float*)d_in[9];
    const float* d2_w     = (const float*)d_in[10];
    const float* d2_b     = (const float*)d_in[11];
    const float* g1_w     = (const float*)d_in[12];
    const float* g1_b     = (const float*)d_in[13];
    const float* g2_w     = (const float*)d_in[14];
    const float* g2_b     = (const float*)d_in[15];

    __hip_bfloat16* x_bf = (__hip_bfloat16*)d_ws;                  // B*N*128 bf16 = 8 MB
    __hip_bfloat16* wbuf = x_bf + (size_t)BB * NN * DM;            // 160 KB bf16 weights
    float* out_res  = (float*)d_out;
    float* out_attn = out_res + (size_t)BB * NN * DM;

    prep_kernel<<<(W_TOTAL + 255) / 256, 256, 0, stream>>>(
        fc1_w, fc2_w, d1_w, d2_w, g1_w, g2_w, wbuf);
    fc1_kernel<<<(BB * NN) / 32, 256, 0, stream>>>(
        features, wbuf + OFF_FC1T, fc1_b, x_bf);
    fused_kernel<<<(BB * NN) / PPB, 256, 0, stream>>>(
        x_bf, xyz, knn_idx, knn_xyz, wbuf,
        d1_b, d2_b, g1_b, g2_b, fc2_b, out_res, out_attn);
}